// Round 1
// baseline (82.428 us; speedup 1.0000x reference)
//
#include <hip/hip_runtime.h>

// RelationalDense: out[n,:] = feat[n,:] @ W[rel[n]] + bias,  W = einsum('rb,bfo', lin, V)
// N=65536, F=64, U=64, R=25, B=8.
//
// R8 (83.8 us): bf16 MFMA, init-free bucket-by-(sb,relation), 2 dispatches.
// R9: amortize per-block fixed cost.
//   - SBN 256->64 (1024 rows/source-block): cells 6400->1600, mean valid 41,
//     CAPB=96 (8.8 sigma over Binomial(1024,1/25); overflow P~1e-18/cell).
//     Wt L2 re-staging 51->12.8 MB, MFMA row-tile fill 64%->85%.
//   - k_main: no sB LDS, no srow LDS. B-fragments (16B/lane, 8KB/block = each
//     Wt byte once) + output row indices read directly from L2; loads issue
//     before the single barrier and overlap feature staging. LDS = sA only
//     (13.8 KB), 1 barrier, __launch_bounds__(256,4).

typedef float v4f __attribute__((ext_vector_type(4)));
typedef short bf16x8 __attribute__((ext_vector_type(8)));
typedef float f32x4 __attribute__((ext_vector_type(4)));
typedef unsigned short u16;
typedef u16 u16x4 __attribute__((ext_vector_type(4)));

#define NN 65536
#define FF 64
#define UU 64
#define RR 25
#define BB 8
#define SBN 64                   // scatter source blocks (1024 rows each)
#define CAPB 96                  // slots per (sb, r) cell; 8.8 sigma above mean 41
#define NSLOT (RR * SBN * CAPB)  // 153600
#define SAS 72                   // LDS row stride in bf16 units (144 B, 16B-aligned)

// ws layout (nothing pre-initialized; validity always derived from bcnt):
//   [0, NSLOT*4)             idx_sorted (int)
//   [BCNT_OFF, +SBN*RR*4)    bcnt[sb][r]  (written unconditionally by k_prep)
//   [WT_OFF, +R*U*F*2)       Wt bf16, transposed [R][U][F]
#define IDX_OFF  0
#define BCNT_OFF (NSLOT * 4)                  // 614400
#define WT_OFF   (BCNT_OFF + SBN * RR * 4)    // 620800 (16B-aligned)
#define WS_NEED  ((size_t)(WT_OFF + RR * FF * UU * 2))

__device__ __forceinline__ u16 f2bf(float x) {
  union { float f; unsigned u; } v; v.f = x;
  unsigned r = v.u + 0x7FFF + ((v.u >> 16) & 1);   // round-to-nearest-even
  return (u16)(r >> 16);
}

// ---------------------------------------------------------------------------
// K1: fused W^T precompute (blocks [0,400)) + init-free bucket scatter
//     (blocks [400,464)). No global atomics, no memset dependency.
// ---------------------------------------------------------------------------
__global__ __launch_bounds__(256) void k_prep(
    const float* __restrict__ kern,   // [B,F,U]
    const float* __restrict__ lin,    // [R,B]
    const int*   __restrict__ rel,    // [N]
    u16*         __restrict__ Wt,     // [R,U,F] bf16
    int*         __restrict__ idx_sorted,
    int*         __restrict__ bcnt) { // [SBN][RR]
  const int wblocks = (RR * FF * UU) / 256;  // 400
  int bid = blockIdx.x;
  if (bid < wblocks) {
    int idx = bid * 256 + threadIdx.x;
    int r = __builtin_amdgcn_readfirstlane(idx >> 12);  // 16 blocks per r
    int f = (idx >> 6) & 63;
    int u = idx & 63;
    float acc = 0.f;
#pragma unroll
    for (int b = 0; b < BB; ++b)
      acc += lin[r * BB + b] * kern[b * (FF * UU) + f * UU + u];  // coalesced in u
    Wt[r * (FF * UU) + u * FF + f] = f2bf(acc);  // transposed write (tiny, 200 KB)
  } else {
    // scatter: LDS histogram -> in-block rank -> deterministic (sb,r) cell
    int sb  = bid - wblocks;
    int tid = threadIdx.x;
    __shared__ int cnt[RR];
    if (tid < RR) cnt[tid] = 0;
    __syncthreads();
#pragma unroll
    for (int j = 0; j < 4; ++j) {
      int row  = sb * 1024 + j * 256 + tid;    // coalesced rel reads
      int r    = rel[row];
      int rank = atomicAdd(&cnt[r], 1);        // LDS atomic, block-local
      if (rank < CAPB)                         // 8.8-sigma guard
        idx_sorted[(r * SBN + sb) * CAPB + rank] = row;
    }
    __syncthreads();
    if (tid < RR) bcnt[sb * RR + tid] = cnt[tid];
  }
}

// ---------------------------------------------------------------------------
// K2: MFMA compute. Block b -> cell (r = b>>6, sb = b&63), up to 96 rows.
// 4 waves = 4 col-tiles of 16; ceil(valid/16) row-tiles execute (mean 3).
// Layouts (verified in R7): A: m=lane&15, k=quad*8+j ; B: n=lane&15 (col),
// same k ; C: col=lane&15, row=quad*4+reg. Bias seeds acc via C-layout.
// B-fragments + row indices come straight from L2 (no sB/srow LDS); only
// the feature tile is staged (fp32->bf16 conversion shared across waves).
// ---------------------------------------------------------------------------
__global__ __launch_bounds__(256, 4) void k_main(
    const float* __restrict__ features,  // [N,F] fp32
    const float* __restrict__ bias,      // [U]
    const u16*   __restrict__ Wt,        // [R,U,F] bf16
    const int*   __restrict__ idx_sorted,
    const int*   __restrict__ bcnt,      // [SBN][RR]
    float*       __restrict__ out) {     // [N,U]
  __shared__ u16 sA[CAPB * SAS];         // feat bf16, 13824 B

  int tid = threadIdx.x;
  int b   = blockIdx.x;
  int r   = __builtin_amdgcn_readfirstlane(b >> 6);  // uniform
  int sb  = b & 63;
  int valid = bcnt[sb * RR + r];                     // uniform -> s_load
  if (valid <= 0) return;                            // empty cell (uniform exit)
  if (valid > CAPB) valid = CAPB;

  int base = (r * SBN + sb) * CAPB;

  int lane = tid & 63;
  int w    = __builtin_amdgcn_readfirstlane(tid >> 6);  // col-tile 0..3
  int m    = lane & 15;
  int quad = lane >> 4;

  // ---- B fragments + bias straight from L2; independent of LDS staging ----
  // elem (u = w*16+m, f = h*32+quad*8) -> Wt[r*4096 + u*64 + h*32 + quad*8]
  const bf16x8* wrow = reinterpret_cast<const bf16x8*>(Wt + (size_t)r * (FF * UU));
  bf16x8 bfrag[2];
#pragma unroll
  for (int h = 0; h < 2; ++h)
    bfrag[h] = wrow[(w * 16 + m) * 8 + h * 4 + quad];
  float bv = bias[w * 16 + m];           // col bias; C-layout col = lane&15

  // ---- stage features fp32->bf16 for valid rows (row idx from L2) ----
  const v4f* f4 = reinterpret_cast<const v4f*>(features);
#pragma unroll
  for (int i = 0; i < 6; ++i) {
    int s   = i * 256 + tid;
    int rl  = s >> 4;                    // local row 0..95
    int seg = s & 15;                    // 4-float segment
    if (rl < valid) {
      int grow = idx_sorted[base + rl];  // 16 adjacent lanes share one addr
      v4f fv = f4[(size_t)grow * 16 + seg];
      u16x4 p = { f2bf(fv[0]), f2bf(fv[1]), f2bf(fv[2]), f2bf(fv[3]) };
      *reinterpret_cast<u16x4*>(&sA[rl * SAS + seg * 4]) = p;
    }
  }
  __syncthreads();

  int nt = (valid + 15) >> 4;            // row-tiles, uniform (1..6, mean ~3)

  for (int t = 0; t < nt; ++t) {
    f32x4 acc = (f32x4){bv, bv, bv, bv};
#pragma unroll
    for (int h = 0; h < 2; ++h) {
      bf16x8 afrag = *reinterpret_cast<const bf16x8*>(
          &sA[(t * 16 + m) * SAS + h * 32 + quad * 8]);
      acc = __builtin_amdgcn_mfma_f32_16x16x32_bf16(afrag, bfrag[h], acc, 0, 0, 0);
    }
#pragma unroll
    for (int g = 0; g < 4; ++g) {
      int orow = t * 16 + quad * 4 + g;
      if (orow < valid) {
        int grow = idx_sorted[base + orow];  // L1-hit broadcast within quad
        out[(size_t)grow * UU + w * 16 + m] = acc[g];  // 16-lane 64B runs
      }
    }
  }
}

// ---------------------------------------------------------------------------
// Fallback (no workspace): fp32 on-the-fly W. Safety net only.
// ---------------------------------------------------------------------------
__global__ __launch_bounds__(256) void k_fallback(
    const float* __restrict__ features,
    const int*   __restrict__ rel,
    const float* __restrict__ kern,
    const float* __restrict__ lin,
    const float* __restrict__ bias,
    float*       __restrict__ out) {
  int tid = threadIdx.x;
  int row = blockIdx.x * 64 + (tid & 63);
  int q   = __builtin_amdgcn_readfirstlane(tid >> 6);
  int r   = rel[row];
  float cf[BB];
#pragma unroll
  for (int b = 0; b < BB; ++b) cf[b] = lin[r * BB + b];
  const v4f* fr = reinterpret_cast<const v4f*>(features + (size_t)row * FF);
  float acc[16];
#pragma unroll
  for (int j = 0; j < 16; ++j) acc[j] = bias[q * 16 + j];
#pragma unroll
  for (int ch = 0; ch < 4; ++ch) {
    v4f fv[4];
#pragma unroll
    for (int k = 0; k < 4; ++k) fv[k] = fr[ch * 4 + k];
#pragma unroll
    for (int k = 0; k < 4; ++k) {
#pragma unroll
      for (int c = 0; c < 4; ++c) {
        int f = ch * 16 + k * 4 + c;
        float fs = fv[k][c];
        float wf[16];
#pragma unroll
        for (int jj = 0; jj < 16; ++jj) wf[jj] = 0.f;
#pragma unroll
        for (int b = 0; b < BB; ++b) {
          const float* Vb = kern + b * (FF * UU) + f * UU + q * 16;
#pragma unroll
          for (int jj = 0; jj < 16; ++jj) wf[jj] += cf[b] * Vb[jj];
        }
#pragma unroll
        for (int jj = 0; jj < 16; ++jj) acc[jj] += fs * wf[jj];
      }
    }
  }
  v4f* o4 = reinterpret_cast<v4f*>(out + (size_t)row * UU + q * 16);
#pragma unroll
  for (int j4 = 0; j4 < 4; ++j4) {
    v4f v = {acc[4 * j4], acc[4 * j4 + 1], acc[4 * j4 + 2], acc[4 * j4 + 3]};
    o4[j4] = v;
  }
}

extern "C" void kernel_launch(void* const* d_in, const int* in_sizes, int n_in,
                              void* d_out, int out_size, void* d_ws, size_t ws_size,
                              hipStream_t stream) {
  const float* features  = (const float*)d_in[0];
  const int*   relations = (const int*)d_in[1];
  const float* kern      = (const float*)d_in[2];
  const float* lin       = (const float*)d_in[3];
  const float* bias      = (const float*)d_in[4];
  float* out = (float*)d_out;

  if (ws_size >= WS_NEED) {
    char* ws         = (char*)d_ws;
    int*  idx_sorted = (int*)(ws + IDX_OFF);
    int*  bcnt       = (int*)(ws + BCNT_OFF);
    u16*  Wt         = (u16*)(ws + WT_OFF);
    k_prep<<<(RR * FF * UU) / 256 + SBN, 256, 0, stream>>>(
        kern, lin, relations, Wt, idx_sorted, bcnt);
    k_main<<<RR * SBN, 256, 0, stream>>>(features, bias, Wt, idx_sorted, bcnt, out);
  } else {
    k_fallback<<<NN / 64, 256, 0, stream>>>(features, relations, kern, lin, bias, out);
  }
}

// Round 3
// 81.549 us; speedup vs baseline: 1.0108x; 1.0108x over previous
//
#include <hip/hip_runtime.h>

// RelationalDense: out[n,:] = feat[n,:] @ W[rel[n]] + bias,  W = einsum('rb,bfo', lin, V)
// N=65536, F=64, U=64, R=25, B=8.
//
// R9 (82.4 us): 2 dispatches + 256 MiB workspace. rocprof showed the top-5
// dispatches are ALL __amd_rocclr_fillBufferAligned writing 256 MiB (~44 us
// each) = harness workspace poison. Our kernels are <5 us combined.
// R10/R11 EXPERIMENT (R10 bench never ran - GPU timeout; resubmitting
// unchanged): zero-workspace, single dispatch. If ws poison is conditional
// on ws use -> ~38-45 us. If unconditional -> ~78-80 us (still saves the
// prep dispatch + gap).
//
// Zero-ws formulation (no precomputed W, no scatter):
//   out[n,:] = bias + sum_b a[rel(n)][b] * (feat[n,:] @ V_b)
// 8 basis GEMMs share the A-side (features); per-row coef combine happens on
// the fp32 accumulators. All global traffic is fully coalesced:
//   feat 16 MB read (sequential), out 16 MB write (sequential), rel 256 KB,
//   V read once per block from L2 (512 x 128 KB = 64 MB L2, ~1.9 us, overlapped).
// MFMA work is 8x the minimal GEMM (4.3 GFLOP) but only ~0.3 us of matrix
// pipe -- kernel stays HBM-bound (32 MB -> 5.2 us floor at 6.3 TB/s).
//
// Block = 128 rows, 512 blocks, 4 waves; wave w owns cols [16w,16w+16).
// MFMA layouts (verified R7): A: m=lane&15 (row), k=quad*8+j (+32h);
// B: n=lane&15 (col), same k; C: col=lane&15, row=quad*4+g.
// VGPR: bfrag 8x2x4=64 + acc 8x4=32 + afrag 8 + temps ~= 120 -> (256,3).
// LDS: sA 128x72 u16 (18.4 KB, pad 72 => afrag b128 conflict-free, same as R9)
//      + scoef 128x8 f32 (4 KB) = 22.5 KB.

typedef float v4f __attribute__((ext_vector_type(4)));
typedef short bf16x8 __attribute__((ext_vector_type(8)));
typedef float f32x4 __attribute__((ext_vector_type(4)));
typedef unsigned short u16;
typedef u16 u16x4 __attribute__((ext_vector_type(4)));

#define NN 65536
#define FF 64
#define UU 64
#define RR 25
#define BB 8
#define ROWS 128                 // rows per block -> 512 blocks, no tail
#define SAS 72                   // LDS row stride in bf16 units (144 B)

__device__ __forceinline__ u16 f2bf(float x) {
  union { float f; unsigned u; } v; v.f = x;
  unsigned r = v.u + 0x7FFF + ((v.u >> 16) & 1);   // round-to-nearest-even
  return (u16)(r >> 16);
}

__global__ __launch_bounds__(256, 3) void k_fused(
    const float* __restrict__ features,  // [N,F] fp32
    const int*   __restrict__ rel,       // [N]
    const float* __restrict__ kern,      // [B,F,U] fp32 (the bases V_b)
    const float* __restrict__ lin,       // [R,B] fp32 (coefs a_rb)
    const float* __restrict__ bias,      // [U]
    float*       __restrict__ out) {     // [N,U]
  __shared__ u16   sA[ROWS * SAS];       // feat bf16, 18432 B
  __shared__ float scoef[ROWS][BB];      // per-row basis coefs, 4096 B

  int tid  = threadIdx.x;
  int row0 = blockIdx.x * ROWS;

  // ---- stage per-row coefs: 2 threads per row (broadcast-friendly reads) ----
  {
    int rl = tid >> 1, half = tid & 1;   // 256 threads / 2 = 128 = ROWS exactly
    int r  = rel[row0 + rl];                       // 2 adjacent lanes share
    const v4f* lv = reinterpret_cast<const v4f*>(lin);
    *reinterpret_cast<v4f*>(&scoef[rl][half * 4]) = lv[r * 2 + half];
  }

  // ---- stage features fp32->bf16, fully coalesced (16 KB/iter/block) ----
  const v4f* f4 = reinterpret_cast<const v4f*>(features);
#pragma unroll
  for (int i = 0; i < (ROWS * 16) / 256; ++i) {    // 8 iters
    int s   = i * 256 + tid;
    int rl  = s >> 4;                              // local row 0..127
    int seg = s & 15;                              // 4-float segment
    v4f fv = f4[(size_t)(row0 + rl) * 16 + seg];
    u16x4 p = { f2bf(fv[0]), f2bf(fv[1]), f2bf(fv[2]), f2bf(fv[3]) };
    *reinterpret_cast<u16x4*>(&sA[rl * SAS + seg * 4]) = p;
  }

  int lane = tid & 63;
  int w    = __builtin_amdgcn_readfirstlane(tid >> 6);  // col-tile 0..3
  int m    = lane & 15;
  int quad = lane >> 4;
  int col  = w * 16 + m;

  // ---- B fragments for all 8 bases straight from global fp32 V ----
  // Each V element is read exactly once per block (64B runs per quad, L2-hot).
  // frag elem j: f = h*32 + quad*8 + j, o = col -> kern[b*4096 + f*64 + col]
  bf16x8 bfrag[BB][2];
#pragma unroll
  for (int b = 0; b < BB; ++b) {
#pragma unroll
    for (int h = 0; h < 2; ++h) {
      const float* vp = kern + b * (FF * UU) + (h * 32 + quad * 8) * UU + col;
      bf16x8 v;
#pragma unroll
      for (int j = 0; j < 8; ++j)
        v[j] = (short)f2bf(vp[j * UU]);            // stride-256B, 64B coalesced
      bfrag[b][h] = v;
    }
  }

  float bv = bias[col];
  __syncthreads();

  const f32x4 zero = (f32x4){0.f, 0.f, 0.f, 0.f};
#pragma unroll
  for (int t = 0; t < ROWS / 16; ++t) {            // 8 row-tiles
    bf16x8 af0 = *reinterpret_cast<const bf16x8*>(&sA[(t * 16 + m) * SAS + quad * 8]);
    bf16x8 af1 = *reinterpret_cast<const bf16x8*>(&sA[(t * 16 + m) * SAS + 32 + quad * 8]);
    f32x4 acc[BB];
#pragma unroll
    for (int b = 0; b < BB; ++b) {                 // 8 independent 2-chains
      acc[b] = __builtin_amdgcn_mfma_f32_16x16x32_bf16(af0, bfrag[b][0], zero, 0, 0, 0);
      acc[b] = __builtin_amdgcn_mfma_f32_16x16x32_bf16(af1, bfrag[b][1], acc[b], 0, 0, 0);
    }
    // ---- per-row coefficient combine + write (C row = quad*4+g) ----
#pragma unroll
    for (int g = 0; g < 4; ++g) {
      int rl = t * 16 + quad * 4 + g;
      v4f c0 = *reinterpret_cast<const v4f*>(&scoef[rl][0]);   // quad-broadcast
      v4f c1 = *reinterpret_cast<const v4f*>(&scoef[rl][4]);
      float o = bv;
      o += c0[0] * acc[0][g] + c0[1] * acc[1][g] + c0[2] * acc[2][g] + c0[3] * acc[3][g];
      o += c1[0] * acc[4][g] + c1[1] * acc[5][g] + c1[2] * acc[6][g] + c1[3] * acc[7][g];
      out[(size_t)(row0 + rl) * UU + col] = o;     // 16-lane 64B runs
    }
  }
}

extern "C" void kernel_launch(void* const* d_in, const int* in_sizes, int n_in,
                              void* d_out, int out_size, void* d_ws, size_t ws_size,
                              hipStream_t stream) {
  const float* features  = (const float*)d_in[0];
  const int*   relations = (const int*)d_in[1];
  const float* kern      = (const float*)d_in[2];
  const float* lin       = (const float*)d_in[3];
  const float* bias      = (const float*)d_in[4];
  float* out = (float*)d_out;
  (void)d_ws; (void)ws_size;   // deliberately unused: testing ws-poison removal

  k_fused<<<NN / ROWS, 256, 0, stream>>>(features, relations, kern, lin, bias, out);
}